// Round 1
// baseline (384.660 us; speedup 1.0000x reference)
//
#include <hip/hip_runtime.h>
#include <stdint.h>

#define T_SEQ 2048
#define NH 16
#define HD 64
#define M_DIM 4096      // B*T
#define K_DIM 1024      // C

typedef __attribute__((ext_vector_type(8))) short bf16x8;
typedef __attribute__((ext_vector_type(4))) float f32x4;
typedef __attribute__((ext_vector_type(4))) unsigned short u16x4;

__device__ __forceinline__ unsigned short f2bf(float f) {
  union { float f; uint32_t u; } x; x.f = f;
  uint32_t u = x.u;
  return (unsigned short)((u + 0x7fffu + ((u >> 16) & 1u)) >> 16);
}

#define GLOAD16(g, l) __builtin_amdgcn_global_load_lds( \
    (const __attribute__((address_space(1))) unsigned int*)(g), \
    (__attribute__((address_space(3))) unsigned int*)(l), 16, 0, 0)

// ---- x fp32 -> bf16 (coalesced, 4 elems/thread) ----
__global__ __launch_bounds__(256) void convert_x_kernel(const float* __restrict__ src,
                                                        unsigned short* __restrict__ dst) {
  int idx = (blockIdx.x * 256 + threadIdx.x) * 4;
  f32x4 v = *(const f32x4*)(src + idx);
  u16x4 o;
  #pragma unroll
  for (int i = 0; i < 4; ++i) o[i] = f2bf(v[i]);
  *(u16x4*)(dst + idx) = o;
}

// ---- transpose + convert: src [R][Cn] f32 -> dst [Cn][R] bf16 ----
__global__ __launch_bounds__(256) void transpose_w_kernel(const float* __restrict__ src,
                                                          unsigned short* __restrict__ dst,
                                                          int R, int Cn) {
  __shared__ float tile[64][65];
  const int r0 = blockIdx.y * 64, c0 = blockIdx.x * 64;
  const int t = threadIdx.x;
  const int rr = t >> 4;          // 0..15
  const int c4 = (t & 15) * 4;    // 0..60
  #pragma unroll
  for (int p = 0; p < 4; ++p) {
    f32x4 v = *(const f32x4*)(src + (size_t)(r0 + p * 16 + rr) * Cn + c0 + c4);
    #pragma unroll
    for (int i = 0; i < 4; ++i) tile[p * 16 + rr][c4 + i] = v[i];
  }
  __syncthreads();
  #pragma unroll
  for (int p = 0; p < 4; ++p) {
    const int cl = p * 16 + rr;
    u16x4 o;
    #pragma unroll
    for (int i = 0; i < 4; ++i) o[i] = f2bf(tile[c4 + i][cl]);
    *(u16x4*)(dst + (size_t)(c0 + cl) * R + r0 + c4) = o;
  }
}

// ---- GEMM: C[M][N] = A[M][K] * Bt[N][K]^T + bias  (bf16 in, fp32 acc) ----
// MODE 0: N=3072, split epilogue -> q[B,H,T,D], k[B,H,T,D], vT[B,H,D,T] (bf16)
// MODE 1: N=1024, fp32 out
template <int MODE>
__global__ __launch_bounds__(256) void gemm_bt_kernel(
    const unsigned short* __restrict__ A,
    const unsigned short* __restrict__ Bt,
    const float* __restrict__ bias,
    unsigned short* __restrict__ qout,
    unsigned short* __restrict__ kout,
    unsigned short* __restrict__ vTout,
    float* __restrict__ fout) {
  __shared__ __align__(16) unsigned short As[128 * 32];
  __shared__ __align__(16) unsigned short Bs[128 * 32];
  const int t = threadIdx.x;
  const int w = t >> 6, l = t & 63;
  const int wr = w >> 1, wc = w & 1;
  const int lr = l & 15, lg = l >> 4;
  const int br = blockIdx.y, bc = blockIdx.x;

  f32x4 acc[4][4];
  const f32x4 zf = {0.f, 0.f, 0.f, 0.f};
  #pragma unroll
  for (int i = 0; i < 4; ++i)
    #pragma unroll
    for (int j = 0; j < 4; ++j) acc[i][j] = zf;

  const int ce = (t & 3) * 8;                    // element offset within 32-wide k row
  const unsigned short* Abase = A + (size_t)(br * 128) * K_DIM;
  const unsigned short* Bbase = Bt + (size_t)(bc * 128) * K_DIM;

  for (int k0 = 0; k0 < K_DIM; k0 += 32) {
    #pragma unroll
    for (int it = 0; it < 2; ++it) {
      const int u = it * 256 + t;                // 16B unit id
      const int row = u >> 2;                    // 4 units per 64B row
      GLOAD16(Abase + (size_t)row * K_DIM + k0 + ce, As + u * 8);
      GLOAD16(Bbase + (size_t)row * K_DIM + k0 + ce, Bs + u * 8);
    }
    __syncthreads();
    bf16x8 af[4], bfv[4];
    #pragma unroll
    for (int f = 0; f < 4; ++f) {
      af[f]  = *(const bf16x8*)(As + (wr * 64 + f * 16 + lr) * 32 + lg * 8);
      bfv[f] = *(const bf16x8*)(Bs + (wc * 64 + f * 16 + lr) * 32 + lg * 8);
    }
    #pragma unroll
    for (int fr = 0; fr < 4; ++fr)
      #pragma unroll
      for (int fc = 0; fc < 4; ++fc)
        acc[fr][fc] = __builtin_amdgcn_mfma_f32_16x16x32_bf16(af[fr], bfv[fc], acc[fr][fc], 0, 0, 0);
    __syncthreads();
  }

  #pragma unroll
  for (int fr = 0; fr < 4; ++fr) {
    #pragma unroll
    for (int fc = 0; fc < 4; ++fc) {
      const int m0 = br * 128 + wr * 64 + fr * 16 + lg * 4;   // row of reg r=0
      const int n  = bc * 128 + wc * 64 + fc * 16 + lr;
      if (MODE == 0) {
        const int which = n >> 10, rem = n & 1023;
        const int h = rem >> 6, d = rem & 63;
        const int b = m0 >> 11, tt0 = m0 & 2047;
        const int bh = b * NH + h;
        if (which == 2) {
          u16x4 pack;
          #pragma unroll
          for (int r = 0; r < 4; ++r) pack[r] = f2bf(acc[fr][fc][r] + bias[n]);
          *(u16x4*)(vTout + ((size_t)bh * HD + d) * T_SEQ + tt0) = pack;
        } else {
          unsigned short* o = (which == 0) ? qout : kout;
          #pragma unroll
          for (int r = 0; r < 4; ++r)
            o[((size_t)bh * T_SEQ + tt0 + r) * HD + d] = f2bf(acc[fr][fc][r] + bias[n]);
        }
      } else {
        #pragma unroll
        for (int r = 0; r < 4; ++r)
          fout[(size_t)(m0 + r) * 1024 + n] = acc[fr][fc][r] + bias[n];
      }
    }
  }
}

// ---- causal flash attention: 4 independent waves/block, 16 q rows/wave ----
// q,k: [B*H, T, D] bf16; vT: [B*H, D, T] bf16; y out: [B, T, H, D] bf16
__global__ __launch_bounds__(256) void flash_attn_kernel(
    const unsigned short* __restrict__ qg,
    const unsigned short* __restrict__ kg,
    const unsigned short* __restrict__ vTg,
    unsigned short* __restrict__ yg) {
  __shared__ __align__(16) unsigned short P[4][16][64];   // per-wave P buffer
  const int t = threadIdx.x;
  const int w = t >> 6, l = t & 63;
  const int lr = l & 15, lg = l >> 4;
  const int bid = blockIdx.x;
  const int qt = bid & 31;        // T/64 q tiles
  const int bh = bid >> 5;
  const int qw = qt * 64 + w * 16;
  const f32x4 zf = {0.f, 0.f, 0.f, 0.f};

  const size_t qoff = ((size_t)bh * T_SEQ + qw + lr) * HD + lg * 8;
  const bf16x8 qf0 = *(const bf16x8*)(qg + qoff);
  const bf16x8 qf1 = *(const bf16x8*)(qg + qoff + 32);

  f32x4 acc[4];
  #pragma unroll
  for (int i = 0; i < 4; ++i) acc[i] = zf;
  float m_run = -3e38f, l_run = 0.f;

  const int ntiles = ((qw + 15) >> 6) + 1;
  const int qrow = qw + lr;

  for (int it = 0; it < ntiles; ++it) {
    const int kv0 = it * 64;
    // S^T tile via swapped mfma(K, Q): lane holds q=lr, tkv = fc*16 + lg*4 + r
    f32x4 s[4];
    #pragma unroll
    for (int fc = 0; fc < 4; ++fc) {
      const size_t kb = ((size_t)bh * T_SEQ + kv0 + fc * 16 + lr) * HD + lg * 8;
      const bf16x8 k0v = *(const bf16x8*)(kg + kb);
      const bf16x8 k1v = *(const bf16x8*)(kg + kb + 32);
      f32x4 sv = zf;
      sv = __builtin_amdgcn_mfma_f32_16x16x32_bf16(k0v, qf0, sv, 0, 0, 0);
      sv = __builtin_amdgcn_mfma_f32_16x16x32_bf16(k1v, qf1, sv, 0, 0, 0);
      s[fc] = sv;
    }
    float pv[4][4];
    float mt = -3e38f;
    #pragma unroll
    for (int fc = 0; fc < 4; ++fc)
      #pragma unroll
      for (int r = 0; r < 4; ++r) {
        float svv = s[fc][r] * 0.125f;          // 1/sqrt(64)
        const int tkv = kv0 + fc * 16 + lg * 4 + r;
        svv = (tkv > qrow) ? -3e38f : svv;
        pv[fc][r] = svv;
        mt = fmaxf(mt, svv);
      }
    mt = fmaxf(mt, __shfl_xor(mt, 16));
    mt = fmaxf(mt, __shfl_xor(mt, 32));
    const float m_new = fmaxf(m_run, mt);
    float ssum = 0.f;
    #pragma unroll
    for (int fc = 0; fc < 4; ++fc)
      #pragma unroll
      for (int r = 0; r < 4; ++r) {
        const float e = __expf(pv[fc][r] - m_new);
        ssum += e;
        P[w][lr][fc * 16 + lg * 4 + r] = f2bf(e);
      }
    ssum += __shfl_xor(ssum, 16);
    ssum += __shfl_xor(ssum, 32);
    const float fac = __expf(m_run - m_new);
    l_run = l_run * fac + ssum;
    m_run = m_new;
    // rescale y acc (acc rows are q = lg*4+r; factor lives in lane lg*4+r)
    float frs[4];
    #pragma unroll
    for (int r = 0; r < 4; ++r) frs[r] = __shfl(fac, lg * 4 + r);
    #pragma unroll
    for (int fd = 0; fd < 4; ++fd)
      #pragma unroll
      for (int r = 0; r < 4; ++r) acc[fd][r] *= frs[r];
    // PV: A = P (row=q=lr, k=tkv chunk), B = V via vT (contiguous)
    const bf16x8 pa0 = *(const bf16x8*)(&P[w][lr][lg * 8]);
    const bf16x8 pa1 = *(const bf16x8*)(&P[w][lr][32 + lg * 8]);
    #pragma unroll
    for (int fd = 0; fd < 4; ++fd) {
      const size_t vb = ((size_t)bh * HD + fd * 16 + lr) * T_SEQ + kv0 + lg * 8;
      const bf16x8 v0 = *(const bf16x8*)(vTg + vb);
      const bf16x8 v1 = *(const bf16x8*)(vTg + vb + 32);
      acc[fd] = __builtin_amdgcn_mfma_f32_16x16x32_bf16(pa0, v0, acc[fd], 0, 0, 0);
      acc[fd] = __builtin_amdgcn_mfma_f32_16x16x32_bf16(pa1, v1, acc[fd], 0, 0, 0);
    }
  }

  const int b = bh >> 4, h = bh & 15;
  #pragma unroll
  for (int r = 0; r < 4; ++r) {
    const float lv = __shfl(l_run, lg * 4 + r);
    const float linv = 1.f / lv;
    const int tt = qw + lg * 4 + r;
    #pragma unroll
    for (int fd = 0; fd < 4; ++fd) {
      const int d = fd * 16 + lr;
      yg[(((size_t)b * T_SEQ + tt) * NH + h) * HD + d] = f2bf(acc[fd][r] * linv);
    }
  }
}

extern "C" void kernel_launch(void* const* d_in, const int* in_sizes, int n_in,
                              void* d_out, int out_size, void* d_ws, size_t ws_size,
                              hipStream_t stream) {
  (void)in_sizes; (void)n_in; (void)out_size; (void)ws_size;
  const float* x      = (const float*)d_in[0];
  const float* w_attn = (const float*)d_in[1];
  const float* b_attn = (const float*)d_in[2];
  const float* w_proj = (const float*)d_in[3];
  const float* b_proj = (const float*)d_in[4];
  float* out = (float*)d_out;

  char* ws = (char*)d_ws;
  unsigned short* xb     = (unsigned short*)(ws);                  // 8 MiB  [4096][1024]
  unsigned short* wqkvT  = (unsigned short*)(ws + (8ull  << 20));  // 6 MiB  [3072][1024]
  unsigned short* wprojT = (unsigned short*)(ws + (14ull << 20));  // 2 MiB  [1024][1024]
  unsigned short* qb     = (unsigned short*)(ws + (16ull << 20));  // 8 MiB  [BH][T][D]
  unsigned short* kb     = (unsigned short*)(ws + (24ull << 20));  // 8 MiB  [BH][T][D]
  unsigned short* vT     = (unsigned short*)(ws + (32ull << 20));  // 8 MiB  [BH][D][T]
  unsigned short* yb     = (unsigned short*)(ws + (40ull << 20));  // 8 MiB  [4096][1024]

  convert_x_kernel<<<4096, 256, 0, stream>>>(x, xb);
  transpose_w_kernel<<<dim3(48, 16), 256, 0, stream>>>(w_attn, wqkvT, 1024, 3072);
  transpose_w_kernel<<<dim3(16, 16), 256, 0, stream>>>(w_proj, wprojT, 1024, 1024);
  gemm_bt_kernel<0><<<dim3(24, 32), 256, 0, stream>>>(xb, wqkvT, b_attn, qb, kb, vT, nullptr);
  flash_attn_kernel<<<1024, 256, 0, stream>>>(qb, kb, vT, yb);
  gemm_bt_kernel<1><<<dim3(8, 32), 256, 0, stream>>>(yb, wprojT, b_proj, nullptr, nullptr, nullptr, out);
}

// Round 2
// 216.204 us; speedup vs baseline: 1.7791x; 1.7791x over previous
//
#include <hip/hip_runtime.h>
#include <stdint.h>

#define T_SEQ 2048
#define NH 16
#define HD 64
#define M_DIM 4096      // B*T
#define K_DIM 1024      // C

typedef __attribute__((ext_vector_type(8))) short bf16x8;
typedef __attribute__((ext_vector_type(4))) float f32x4;
typedef __attribute__((ext_vector_type(4))) unsigned short u16x4;

__device__ __forceinline__ unsigned short f2bf(float f) {
  union { float f; uint32_t u; } x; x.f = f;
  uint32_t u = x.u;
  return (unsigned short)((u + 0x7fffu + ((u >> 16) & 1u)) >> 16);
}

#define GLOAD16(g, l) __builtin_amdgcn_global_load_lds( \
    (const __attribute__((address_space(1))) unsigned int*)(g), \
    (__attribute__((address_space(3))) unsigned int*)(l), 16, 0, 0)

// ---- x fp32 -> bf16 (coalesced, 4 elems/thread) ----
__global__ __launch_bounds__(256) void convert_x_kernel(const float* __restrict__ src,
                                                        unsigned short* __restrict__ dst) {
  int idx = (blockIdx.x * 256 + threadIdx.x) * 4;
  f32x4 v = *(const f32x4*)(src + idx);
  u16x4 o;
  #pragma unroll
  for (int i = 0; i < 4; ++i) o[i] = f2bf(v[i]);
  *(u16x4*)(dst + idx) = o;
}

// ---- transpose + convert: src [R][Cn] f32 -> dst [Cn][R] bf16 ----
__global__ __launch_bounds__(256) void transpose_w_kernel(const float* __restrict__ src,
                                                          unsigned short* __restrict__ dst,
                                                          int R, int Cn) {
  __shared__ float tile[64][65];
  const int r0 = blockIdx.y * 64, c0 = blockIdx.x * 64;
  const int t = threadIdx.x;
  const int rr = t >> 4;          // 0..15
  const int c4 = (t & 15) * 4;    // 0..60
  #pragma unroll
  for (int p = 0; p < 4; ++p) {
    f32x4 v = *(const f32x4*)(src + (size_t)(r0 + p * 16 + rr) * Cn + c0 + c4);
    #pragma unroll
    for (int i = 0; i < 4; ++i) tile[p * 16 + rr][c4 + i] = v[i];
  }
  __syncthreads();
  #pragma unroll
  for (int p = 0; p < 4; ++p) {
    const int cl = p * 16 + rr;
    u16x4 o;
    #pragma unroll
    for (int i = 0; i < 4; ++i) o[i] = f2bf(tile[c4 + i][cl]);
    *(u16x4*)(dst + (size_t)(c0 + cl) * R + r0 + c4) = o;
  }
}

// ---- GEMM: C[M][N] = A[M][K] * Bt[N][K]^T + bias  (bf16 in, fp32 acc) ----
template <int MODE>
__global__ __launch_bounds__(256) void gemm_bt_kernel(
    const unsigned short* __restrict__ A,
    const unsigned short* __restrict__ Bt,
    const float* __restrict__ bias,
    unsigned short* __restrict__ qout,
    unsigned short* __restrict__ kout,
    unsigned short* __restrict__ vTout,
    float* __restrict__ fout) {
  __shared__ __align__(16) unsigned short As[128 * 32];
  __shared__ __align__(16) unsigned short Bs[128 * 32];
  const int t = threadIdx.x;
  const int w = t >> 6, l = t & 63;
  const int wr = w >> 1, wc = w & 1;
  const int lr = l & 15, lg = l >> 4;
  const int br = blockIdx.y, bc = blockIdx.x;

  f32x4 acc[4][4];
  const f32x4 zf = {0.f, 0.f, 0.f, 0.f};
  #pragma unroll
  for (int i = 0; i < 4; ++i)
    #pragma unroll
    for (int j = 0; j < 4; ++j) acc[i][j] = zf;

  const int ce = (t & 3) * 8;
  const unsigned short* Abase = A + (size_t)(br * 128) * K_DIM;
  const unsigned short* Bbase = Bt + (size_t)(bc * 128) * K_DIM;

  for (int k0 = 0; k0 < K_DIM; k0 += 32) {
    #pragma unroll
    for (int it = 0; it < 2; ++it) {
      const int u = it * 256 + t;
      const int row = u >> 2;
      GLOAD16(Abase + (size_t)row * K_DIM + k0 + ce, As + u * 8);
      GLOAD16(Bbase + (size_t)row * K_DIM + k0 + ce, Bs + u * 8);
    }
    __syncthreads();
    bf16x8 af[4], bfv[4];
    #pragma unroll
    for (int f = 0; f < 4; ++f) {
      af[f]  = *(const bf16x8*)(As + (wr * 64 + f * 16 + lr) * 32 + lg * 8);
      bfv[f] = *(const bf16x8*)(Bs + (wc * 64 + f * 16 + lr) * 32 + lg * 8);
    }
    #pragma unroll
    for (int fr = 0; fr < 4; ++fr)
      #pragma unroll
      for (int fc = 0; fc < 4; ++fc)
        acc[fr][fc] = __builtin_amdgcn_mfma_f32_16x16x32_bf16(af[fr], bfv[fc], acc[fr][fc], 0, 0, 0);
    __syncthreads();
  }

  #pragma unroll
  for (int fr = 0; fr < 4; ++fr) {
    #pragma unroll
    for (int fc = 0; fc < 4; ++fc) {
      const int m0 = br * 128 + wr * 64 + fr * 16 + lg * 4;
      const int n  = bc * 128 + wc * 64 + fc * 16 + lr;
      if (MODE == 0) {
        const int which = n >> 10, rem = n & 1023;
        const int h = rem >> 6, d = rem & 63;
        const int b = m0 >> 11, tt0 = m0 & 2047;
        const int bh = b * NH + h;
        if (which == 2) {
          u16x4 pack;
          #pragma unroll
          for (int r = 0; r < 4; ++r) pack[r] = f2bf(acc[fr][fc][r] + bias[n]);
          *(u16x4*)(vTout + ((size_t)bh * HD + d) * T_SEQ + tt0) = pack;
        } else {
          unsigned short* o = (which == 0) ? qout : kout;
          #pragma unroll
          for (int r = 0; r < 4; ++r)
            o[((size_t)bh * T_SEQ + tt0 + r) * HD + d] = f2bf(acc[fr][fc][r] + bias[n]);
        }
      } else {
        #pragma unroll
        for (int r = 0; r < 4; ++r)
          fout[(size_t)(m0 + r) * 1024 + n] = acc[fr][fc][r] + bias[n];
      }
    }
  }
}

// ---- causal flash attention, v2 ----
// 512 blocks: each block = one (bh, tile-pair). 4 waves, 16 q-rows/wave.
// K/V tiles staged in LDS (double-buffered, global_load_lds, XOR-swizzled
// via pre-swizzled global source). Pairing (pid, 31-pid) balances causal work.
__global__ __launch_bounds__(256) void flash_attn_kernel(
    const unsigned short* __restrict__ qg,
    const unsigned short* __restrict__ kg,
    const unsigned short* __restrict__ vTg,
    unsigned short* __restrict__ yg) {
  __shared__ __align__(16) unsigned short Ks[2][64 * 64];  // 8 KiB each
  __shared__ __align__(16) unsigned short Vs[2][64 * 64];
  __shared__ __align__(16) unsigned short P[4][16][64];    // per-wave P

  const int t = threadIdx.x;
  const int w = t >> 6, l = t & 63;
  const int lr = l & 15, lg = l >> 4;
  // bh-major XCD swizzle: XCD x gets 4 consecutive bh's (2 MiB K+V in its L2)
  const int lb = (blockIdx.x & 7) * 64 + (blockIdx.x >> 3);
  const int pid = lb & 15;
  const int bh = lb >> 4;
  const int swz = lr & 7;

  // staging geometry: 256 threads x 16B = 32 rows of 128B per shot, 2 shots/tile
  const int srow0 = t >> 3;        // 0..31
  const int sch = t & 7;           // 16B chunk within 128B row

  const size_t kgb = (size_t)bh * T_SEQ * HD;
  const size_t vgb = (size_t)bh * HD * T_SEQ;

  #pragma unroll 1
  for (int ph = 0; ph < 2; ++ph) {
    const int qt = ph ? (31 - pid) : pid;
    const int nt = qt + 1;
    const int qw = qt * 64 + w * 16;
    const int qrow = qw + lr;

    const size_t qoff = ((size_t)bh * T_SEQ + qw + lr) * HD + lg * 8;
    const bf16x8 qf0 = *(const bf16x8*)(qg + qoff);
    const bf16x8 qf1 = *(const bf16x8*)(qg + qoff + 32);

    f32x4 acc[4];
    const f32x4 zf = {0.f, 0.f, 0.f, 0.f};
    #pragma unroll
    for (int i = 0; i < 4; ++i) acc[i] = zf;
    float m_run = -3e38f, l_run = 0.f;

    // prologue: stage tile 0 into buf 0
    #pragma unroll
    for (int sh = 0; sh < 2; ++sh) {
      const int row = sh * 32 + srow0;
      const int sc = (sch ^ (row & 7)) * 8;
      GLOAD16(kg + kgb + (size_t)row * HD + sc, Ks[0] + row * 64 + sch * 8);
      GLOAD16(vTg + vgb + (size_t)row * T_SEQ + sc, Vs[0] + row * 64 + sch * 8);
    }
    __syncthreads();

    int cur = 0;
    #pragma unroll 1
    for (int it = 0; it < nt; ++it) {
      const int kv0 = it * 64;
      if (it + 1 < nt) {
        const int kvn = kv0 + 64;
        #pragma unroll
        for (int sh = 0; sh < 2; ++sh) {
          const int row = sh * 32 + srow0;
          const int sc = (sch ^ (row & 7)) * 8;
          GLOAD16(kg + kgb + (size_t)(kvn + row) * HD + sc, Ks[cur ^ 1] + row * 64 + sch * 8);
          GLOAD16(vTg + vgb + (size_t)row * T_SEQ + kvn + sc, Vs[cur ^ 1] + row * 64 + sch * 8);
        }
      }

      // QK^T (swapped): s[fc] -> lane holds (q=lr, tkv = kv0 + fc*16 + lg*4 + r)
      f32x4 s[4];
      __builtin_amdgcn_s_setprio(1);
      #pragma unroll
      for (int fc = 0; fc < 4; ++fc) {
        const unsigned short* kr = Ks[cur] + (fc * 16 + lr) * 64;
        const bf16x8 k0v = *(const bf16x8*)(kr + ((lg ^ swz) * 8));
        const bf16x8 k1v = *(const bf16x8*)(kr + (((lg + 4) ^ swz) * 8));
        f32x4 sv = zf;
        sv = __builtin_amdgcn_mfma_f32_16x16x32_bf16(k0v, qf0, sv, 0, 0, 0);
        sv = __builtin_amdgcn_mfma_f32_16x16x32_bf16(k1v, qf1, sv, 0, 0, 0);
        s[fc] = sv;
      }
      __builtin_amdgcn_s_setprio(0);

      float pvv[4][4];
      float mt = -3e38f;
      #pragma unroll
      for (int fc = 0; fc < 4; ++fc)
        #pragma unroll
        for (int r = 0; r < 4; ++r) {
          float sv = s[fc][r] * 0.125f;                 // 1/sqrt(64)
          const int tkv = kv0 + fc * 16 + lg * 4 + r;
          sv = (tkv > qrow) ? -3e38f : sv;
          pvv[fc][r] = sv;
          mt = fmaxf(mt, sv);
        }
      mt = fmaxf(mt, __shfl_xor(mt, 16));
      mt = fmaxf(mt, __shfl_xor(mt, 32));
      const float m_new = fmaxf(m_run, mt);
      float ssum = 0.f;
      #pragma unroll
      for (int fc = 0; fc < 4; ++fc) {
        u16x4 pk;
        #pragma unroll
        for (int r = 0; r < 4; ++r) {
          const float e = __expf(pvv[fc][r] - m_new);
          ssum += e;
          pk[r] = f2bf(e);
        }
        *(u16x4*)&P[w][lr][(fc * 16 + lg * 4) ^ ((lr & 3) << 4)] = pk;
      }
      ssum += __shfl_xor(ssum, 16);
      ssum += __shfl_xor(ssum, 32);
      const float fac = __expf(m_run - m_new);
      l_run = l_run * fac + ssum;
      m_run = m_new;
      float frs[4];
      #pragma unroll
      for (int r = 0; r < 4; ++r) frs[r] = __shfl(fac, lg * 4 + r);
      #pragma unroll
      for (int fd = 0; fd < 4; ++fd)
        #pragma unroll
        for (int r = 0; r < 4; ++r) acc[fd][r] *= frs[r];

      // PV: A = P (q=lr rows), B = V from swizzled vT tile
      const bf16x8 pa0 = *(const bf16x8*)&P[w][lr][(lg * 8) ^ ((lr & 3) << 4)];
      const bf16x8 pa1 = *(const bf16x8*)&P[w][lr][(32 + lg * 8) ^ ((lr & 3) << 4)];
      __builtin_amdgcn_s_setprio(1);
      #pragma unroll
      for (int fd = 0; fd < 4; ++fd) {
        const unsigned short* vr = Vs[cur] + (fd * 16 + lr) * 64;
        const bf16x8 v0 = *(const bf16x8*)(vr + ((lg ^ swz) * 8));
        const bf16x8 v1 = *(const bf16x8*)(vr + (((lg + 4) ^ swz) * 8));
        acc[fd] = __builtin_amdgcn_mfma_f32_16x16x32_bf16(pa0, v0, acc[fd], 0, 0, 0);
        acc[fd] = __builtin_amdgcn_mfma_f32_16x16x32_bf16(pa1, v1, acc[fd], 0, 0, 0);
      }
      __builtin_amdgcn_s_setprio(0);
      __syncthreads();   // drains vmcnt (stage landed) + protects buf reuse
      cur ^= 1;
    }

    const int b = bh >> 4, h = bh & 15;
    #pragma unroll
    for (int r = 0; r < 4; ++r) {
      const float lv = __shfl(l_run, lg * 4 + r);
      const float linv = 1.f / lv;
      const int tt = qw + lg * 4 + r;
      #pragma unroll
      for (int fd = 0; fd < 4; ++fd) {
        const int d = fd * 16 + lr;
        yg[(((size_t)b * T_SEQ + tt) * NH + h) * HD + d] = f2bf(acc[fd][r] * linv);
      }
    }
    __syncthreads();   // before next phase restages buf 0
  }
}

extern "C" void kernel_launch(void* const* d_in, const int* in_sizes, int n_in,
                              void* d_out, int out_size, void* d_ws, size_t ws_size,
                              hipStream_t stream) {
  (void)in_sizes; (void)n_in; (void)out_size; (void)ws_size;
  const float* x      = (const float*)d_in[0];
  const float* w_attn = (const float*)d_in[1];
  const float* b_attn = (const float*)d_in[2];
  const float* w_proj = (const float*)d_in[3];
  const float* b_proj = (const float*)d_in[4];
  float* out = (float*)d_out;

  char* ws = (char*)d_ws;
  unsigned short* xb     = (unsigned short*)(ws);                  // 8 MiB  [4096][1024]
  unsigned short* wqkvT  = (unsigned short*)(ws + (8ull  << 20));  // 6 MiB  [3072][1024]
  unsigned short* wprojT = (unsigned short*)(ws + (14ull << 20));  // 2 MiB  [1024][1024]
  unsigned short* qb     = (unsigned short*)(ws + (16ull << 20));  // 8 MiB  [BH][T][D]
  unsigned short* kb     = (unsigned short*)(ws + (24ull << 20));  // 8 MiB  [BH][T][D]
  unsigned short* vT     = (unsigned short*)(ws + (32ull << 20));  // 8 MiB  [BH][D][T]
  unsigned short* yb     = (unsigned short*)(ws + (40ull << 20));  // 8 MiB  [4096][1024]

  convert_x_kernel<<<4096, 256, 0, stream>>>(x, xb);
  transpose_w_kernel<<<dim3(48, 16), 256, 0, stream>>>(w_attn, wqkvT, 1024, 3072);
  transpose_w_kernel<<<dim3(16, 16), 256, 0, stream>>>(w_proj, wprojT, 1024, 1024);
  gemm_bt_kernel<0><<<dim3(24, 32), 256, 0, stream>>>(xb, wqkvT, b_attn, qb, kb, vT, nullptr);
  flash_attn_kernel<<<512, 256, 0, stream>>>(qb, kb, vT, yb);
  gemm_bt_kernel<1><<<dim3(8, 32), 256, 0, stream>>>(yb, wprojT, b_proj, nullptr, nullptr, nullptr, out);
}

// Round 3
// 202.229 us; speedup vs baseline: 1.9021x; 1.0691x over previous
//
#include <hip/hip_runtime.h>
#include <stdint.h>

#define T_SEQ 2048
#define NH 16
#define HD 64
#define M_DIM 4096      // B*T
#define K_DIM 1024      // C

typedef __attribute__((ext_vector_type(8))) short bf16x8;
typedef __attribute__((ext_vector_type(4))) float f32x4;
typedef __attribute__((ext_vector_type(4))) unsigned short u16x4;

__device__ __forceinline__ unsigned short f2bf(float f) {
  union { float f; uint32_t u; } x; x.f = f;
  uint32_t u = x.u;
  return (unsigned short)((u + 0x7fffu + ((u >> 16) & 1u)) >> 16);
}

__device__ __forceinline__ uint32_t cvtpk_bf16(float a, float b) {
  uint32_t r;
  asm("v_cvt_pk_bf16_f32 %0, %1, %2" : "=v"(r) : "v"(a), "v"(b));
  return r;
}

#define GLOAD16(g, l) __builtin_amdgcn_global_load_lds( \
    (const __attribute__((address_space(1))) unsigned int*)(g), \
    (__attribute__((address_space(3))) unsigned int*)(l), 16, 0, 0)

// ---- x fp32 -> bf16 (coalesced, 4 elems/thread) ----
__global__ __launch_bounds__(256) void convert_x_kernel(const float* __restrict__ src,
                                                        unsigned short* __restrict__ dst) {
  int idx = (blockIdx.x * 256 + threadIdx.x) * 4;
  f32x4 v = *(const f32x4*)(src + idx);
  u16x4 o;
  #pragma unroll
  for (int i = 0; i < 4; ++i) o[i] = f2bf(v[i]);
  *(u16x4*)(dst + idx) = o;
}

// ---- transpose + convert: src [R][Cn] f32 -> dst [Cn][R] bf16 ----
__global__ __launch_bounds__(256) void transpose_w_kernel(const float* __restrict__ src,
                                                          unsigned short* __restrict__ dst,
                                                          int R, int Cn) {
  __shared__ float tile[64][65];
  const int r0 = blockIdx.y * 64, c0 = blockIdx.x * 64;
  const int t = threadIdx.x;
  const int rr = t >> 4;          // 0..15
  const int c4 = (t & 15) * 4;    // 0..60
  #pragma unroll
  for (int p = 0; p < 4; ++p) {
    f32x4 v = *(const f32x4*)(src + (size_t)(r0 + p * 16 + rr) * Cn + c0 + c4);
    #pragma unroll
    for (int i = 0; i < 4; ++i) tile[p * 16 + rr][c4 + i] = v[i];
  }
  __syncthreads();
  #pragma unroll
  for (int p = 0; p < 4; ++p) {
    const int cl = p * 16 + rr;
    u16x4 o;
    #pragma unroll
    for (int i = 0; i < 4; ++i) o[i] = f2bf(tile[c4 + i][cl]);
    *(u16x4*)(dst + (size_t)(c0 + cl) * R + r0 + c4) = o;
  }
}

// ---- GEMM: C[M][N] = A[M][K] * Bt[N][K]^T + bias  (bf16 in, fp32 acc) ----
// MODE 0: q rows get pre-scaled by 0.125*log2(e) (softmax runs in exp2 domain)
template <int MODE>
__global__ __launch_bounds__(256) void gemm_bt_kernel(
    const unsigned short* __restrict__ A,
    const unsigned short* __restrict__ Bt,
    const float* __restrict__ bias,
    unsigned short* __restrict__ qout,
    unsigned short* __restrict__ kout,
    unsigned short* __restrict__ vTout,
    float* __restrict__ fout) {
  __shared__ __align__(16) unsigned short As[128 * 32];
  __shared__ __align__(16) unsigned short Bs[128 * 32];
  const int t = threadIdx.x;
  const int w = t >> 6, l = t & 63;
  const int wr = w >> 1, wc = w & 1;
  const int lr = l & 15, lg = l >> 4;
  const int br = blockIdx.y, bc = blockIdx.x;

  f32x4 acc[4][4];
  const f32x4 zf = {0.f, 0.f, 0.f, 0.f};
  #pragma unroll
  for (int i = 0; i < 4; ++i)
    #pragma unroll
    for (int j = 0; j < 4; ++j) acc[i][j] = zf;

  const int ce = (t & 3) * 8;
  const unsigned short* Abase = A + (size_t)(br * 128) * K_DIM;
  const unsigned short* Bbase = Bt + (size_t)(bc * 128) * K_DIM;

  for (int k0 = 0; k0 < K_DIM; k0 += 32) {
    #pragma unroll
    for (int it = 0; it < 2; ++it) {
      const int u = it * 256 + t;
      const int row = u >> 2;
      GLOAD16(Abase + (size_t)row * K_DIM + k0 + ce, As + u * 8);
      GLOAD16(Bbase + (size_t)row * K_DIM + k0 + ce, Bs + u * 8);
    }
    __syncthreads();
    bf16x8 af[4], bfv[4];
    #pragma unroll
    for (int f = 0; f < 4; ++f) {
      af[f]  = *(const bf16x8*)(As + (wr * 64 + f * 16 + lr) * 32 + lg * 8);
      bfv[f] = *(const bf16x8*)(Bs + (wc * 64 + f * 16 + lr) * 32 + lg * 8);
    }
    #pragma unroll
    for (int fr = 0; fr < 4; ++fr)
      #pragma unroll
      for (int fc = 0; fc < 4; ++fc)
        acc[fr][fc] = __builtin_amdgcn_mfma_f32_16x16x32_bf16(af[fr], bfv[fc], acc[fr][fc], 0, 0, 0);
    __syncthreads();
  }

  #pragma unroll
  for (int fr = 0; fr < 4; ++fr) {
    #pragma unroll
    for (int fc = 0; fc < 4; ++fc) {
      const int m0 = br * 128 + wr * 64 + fr * 16 + lg * 4;
      const int n  = bc * 128 + wc * 64 + fc * 16 + lr;
      if (MODE == 0) {
        const int which = n >> 10, rem = n & 1023;
        const int h = rem >> 6, d = rem & 63;
        const int b = m0 >> 11, tt0 = m0 & 2047;
        const int bh = b * NH + h;
        if (which == 2) {
          u16x4 pack;
          #pragma unroll
          for (int r = 0; r < 4; ++r) pack[r] = f2bf(acc[fr][fc][r] + bias[n]);
          *(u16x4*)(vTout + ((size_t)bh * HD + d) * T_SEQ + tt0) = pack;
        } else {
          unsigned short* o = (which == 0) ? qout : kout;
          const float sc = (which == 0) ? 0.18033688011112042f : 1.0f;  // 0.125*log2(e)
          #pragma unroll
          for (int r = 0; r < 4; ++r)
            o[((size_t)bh * T_SEQ + tt0 + r) * HD + d] = f2bf((acc[fr][fc][r] + bias[n]) * sc);
        }
      } else {
        #pragma unroll
        for (int r = 0; r < 4; ++r)
          fout[(size_t)(m0 + r) * 1024 + n] = acc[fr][fc][r] + bias[n];
      }
    }
  }
}

// ---- causal flash attention, v3: exp2-domain softmax + defer-max + cvt_pk ----
__global__ __launch_bounds__(256) void flash_attn_kernel(
    const unsigned short* __restrict__ qg,
    const unsigned short* __restrict__ kg,
    const unsigned short* __restrict__ vTg,
    unsigned short* __restrict__ yg) {
  __shared__ __align__(16) unsigned short Ks[2][64 * 64];
  __shared__ __align__(16) unsigned short Vs[2][64 * 64];
  __shared__ __align__(16) unsigned short P[4][16][64];

  const int t = threadIdx.x;
  const int w = t >> 6, l = t & 63;
  const int lr = l & 15, lg = l >> 4;
  const int lb = (blockIdx.x & 7) * 64 + (blockIdx.x >> 3);  // XCD swizzle
  const int pid = lb & 15;
  const int bh = lb >> 4;
  const int swz = lr & 7;

  const int srow0 = t >> 3;
  const int sch = t & 7;

  const size_t kgb = (size_t)bh * T_SEQ * HD;
  const size_t vgb = (size_t)bh * HD * T_SEQ;
  const f32x4 zf = {0.f, 0.f, 0.f, 0.f};

  #pragma unroll 1
  for (int ph = 0; ph < 2; ++ph) {
    const int qt = ph ? (31 - pid) : pid;
    const int nt = qt + 1;
    const int qw = qt * 64 + w * 16;
    const int qrow = qw + lr;

    const size_t qoff = ((size_t)bh * T_SEQ + qw + lr) * HD + lg * 8;
    const bf16x8 qf0 = *(const bf16x8*)(qg + qoff);      // pre-scaled by 0.125*log2e
    const bf16x8 qf1 = *(const bf16x8*)(qg + qoff + 32);

    f32x4 acc[4];
    #pragma unroll
    for (int i = 0; i < 4; ++i) acc[i] = zf;
    float m_run = 0.f;      // defer-max: start at 0, rescale only past THR
    float l_part = 0.f;     // per-lane partial denominator

    #pragma unroll
    for (int sh = 0; sh < 2; ++sh) {
      const int row = sh * 32 + srow0;
      const int sc = (sch ^ (row & 7)) * 8;
      GLOAD16(kg + kgb + (size_t)row * HD + sc, Ks[0] + row * 64 + sch * 8);
      GLOAD16(vTg + vgb + (size_t)row * T_SEQ + sc, Vs[0] + row * 64 + sch * 8);
    }
    __syncthreads();

    int cur = 0;
    #pragma unroll 1
    for (int it = 0; it < nt; ++it) {
      const int kv0 = it * 64;
      if (it + 1 < nt) {
        const int kvn = kv0 + 64;
        #pragma unroll
        for (int sh = 0; sh < 2; ++sh) {
          const int row = sh * 32 + srow0;
          const int sc = (sch ^ (row & 7)) * 8;
          GLOAD16(kg + kgb + (size_t)(kvn + row) * HD + sc, Ks[cur ^ 1] + row * 64 + sch * 8);
          GLOAD16(vTg + vgb + (size_t)row * T_SEQ + kvn + sc, Vs[cur ^ 1] + row * 64 + sch * 8);
        }
      }

      // QK^T (swapped): lane holds (q=lr, tkv = kv0 + fc*16 + lg*4 + r), exp2 domain
      f32x4 s[4];
      __builtin_amdgcn_s_setprio(1);
      #pragma unroll
      for (int fc = 0; fc < 4; ++fc) {
        const unsigned short* kr = Ks[cur] + (fc * 16 + lr) * 64;
        const bf16x8 k0v = *(const bf16x8*)(kr + ((lg ^ swz) * 8));
        const bf16x8 k1v = *(const bf16x8*)(kr + (((lg + 4) ^ swz) * 8));
        f32x4 sv = zf;
        sv = __builtin_amdgcn_mfma_f32_16x16x32_bf16(k0v, qf0, sv, 0, 0, 0);
        sv = __builtin_amdgcn_mfma_f32_16x16x32_bf16(k1v, qf1, sv, 0, 0, 0);
        s[fc] = sv;
      }
      __builtin_amdgcn_s_setprio(0);

      // causal mask: only the diagonal tile needs it (wave-uniform branch)
      if (it == nt - 1) {
        #pragma unroll
        for (int fc = 0; fc < 4; ++fc)
          #pragma unroll
          for (int r = 0; r < 4; ++r) {
            const int tkv = kv0 + fc * 16 + lg * 4 + r;
            if (tkv > qrow) s[fc][r] = -1e30f;
          }
      }

      // defer-max check (T13): local max only; rescale path is rare
      float mt = s[0][0];
      #pragma unroll
      for (int fc = 0; fc < 4; ++fc)
        #pragma unroll
        for (int r = 0; r < 4; ++r) mt = fmaxf(mt, s[fc][r]);
      if (__any(mt > m_run + 8.f)) {
        float mrow = fmaxf(mt, __shfl_xor(mt, 16));
        mrow = fmaxf(mrow, __shfl_xor(mrow, 32));
        const float m_new = fmaxf(m_run, mrow);
        const float fac = __builtin_amdgcn_exp2f(m_run - m_new);
        l_part *= fac;
        float frs[4];
        #pragma unroll
        for (int r = 0; r < 4; ++r) frs[r] = __shfl(fac, lg * 4 + r);
        #pragma unroll
        for (int fd = 0; fd < 4; ++fd)
          #pragma unroll
          for (int r = 0; r < 4; ++r) acc[fd][r] *= frs[r];
        m_run = m_new;
      }

      // P = exp2(s - m), pack via v_cvt_pk_bf16_f32, accumulate partial sum
      #pragma unroll
      for (int fc = 0; fc < 4; ++fc) {
        float e0 = __builtin_amdgcn_exp2f(s[fc][0] - m_run);
        float e1 = __builtin_amdgcn_exp2f(s[fc][1] - m_run);
        float e2 = __builtin_amdgcn_exp2f(s[fc][2] - m_run);
        float e3 = __builtin_amdgcn_exp2f(s[fc][3] - m_run);
        l_part += (e0 + e1) + (e2 + e3);
        uint2 pk;
        pk.x = cvtpk_bf16(e0, e1);
        pk.y = cvtpk_bf16(e2, e3);
        *(uint2*)&P[w][lr][(fc * 16 + lg * 4) ^ ((lr & 3) << 4)] = pk;
      }

      // PV
      const bf16x8 pa0 = *(const bf16x8*)&P[w][lr][(lg * 8) ^ ((lr & 3) << 4)];
      const bf16x8 pa1 = *(const bf16x8*)&P[w][lr][(32 + lg * 8) ^ ((lr & 3) << 4)];
      __builtin_amdgcn_s_setprio(1);
      #pragma unroll
      for (int fd = 0; fd < 4; ++fd) {
        const unsigned short* vr = Vs[cur] + (fd * 16 + lr) * 64;
        const bf16x8 v0 = *(const bf16x8*)(vr + ((lg ^ swz) * 8));
        const bf16x8 v1 = *(const bf16x8*)(vr + (((lg + 4) ^ swz) * 8));
        acc[fd] = __builtin_amdgcn_mfma_f32_16x16x32_bf16(pa0, v0, acc[fd], 0, 0, 0);
        acc[fd] = __builtin_amdgcn_mfma_f32_16x16x32_bf16(pa1, v1, acc[fd], 0, 0, 0);
      }
      __builtin_amdgcn_s_setprio(0);
      __syncthreads();
      cur ^= 1;
    }

    // final denominator reduce (once per phase, not per tile)
    float lsum = l_part;
    lsum += __shfl_xor(lsum, 16);
    lsum += __shfl_xor(lsum, 32);

    const int b = bh >> 4, h = bh & 15;
    #pragma unroll
    for (int r = 0; r < 4; ++r) {
      const float lv = __shfl(lsum, lg * 4 + r);
      const float linv = 1.f / lv;
      const int tt = qw + lg * 4 + r;
      #pragma unroll
      for (int fd = 0; fd < 4; ++fd) {
        const int d = fd * 16 + lr;
        yg[(((size_t)b * T_SEQ + tt) * NH + h) * HD + d] = f2bf(acc[fd][r] * linv);
      }
    }
    __syncthreads();
  }
}

extern "C" void kernel_launch(void* const* d_in, const int* in_sizes, int n_in,
                              void* d_out, int out_size, void* d_ws, size_t ws_size,
                              hipStream_t stream) {
  (void)in_sizes; (void)n_in; (void)out_size; (void)ws_size;
  const float* x      = (const float*)d_in[0];
  const float* w_attn = (const float*)d_in[1];
  const float* b_attn = (const float*)d_in[2];
  const float* w_proj = (const float*)d_in[3];
  const float* b_proj = (const float*)d_in[4];
  float* out = (float*)d_out;

  char* ws = (char*)d_ws;
  unsigned short* xb     = (unsigned short*)(ws);                  // 8 MiB  [4096][1024]
  unsigned short* wqkvT  = (unsigned short*)(ws + (8ull  << 20));  // 6 MiB  [3072][1024]
  unsigned short* wprojT = (unsigned short*)(ws + (14ull << 20));  // 2 MiB  [1024][1024]
  unsigned short* qb     = (unsigned short*)(ws + (16ull << 20));  // 8 MiB  [BH][T][D]
  unsigned short* kb     = (unsigned short*)(ws + (24ull << 20));  // 8 MiB  [BH][T][D]
  unsigned short* vT     = (unsigned short*)(ws + (32ull << 20));  // 8 MiB  [BH][D][T]
  unsigned short* yb     = (unsigned short*)(ws + (40ull << 20));  // 8 MiB  [4096][1024]

  convert_x_kernel<<<4096, 256, 0, stream>>>(x, xb);
  transpose_w_kernel<<<dim3(48, 16), 256, 0, stream>>>(w_attn, wqkvT, 1024, 3072);
  transpose_w_kernel<<<dim3(16, 16), 256, 0, stream>>>(w_proj, wprojT, 1024, 1024);
  gemm_bt_kernel<0><<<dim3(24, 32), 256, 0, stream>>>(xb, wqkvT, b_attn, qb, kb, vT, nullptr);
  flash_attn_kernel<<<512, 256, 0, stream>>>(qb, kb, vT, yb);
  gemm_bt_kernel<1><<<dim3(8, 32), 256, 0, stream>>>(yb, wprojT, b_proj, nullptr, nullptr, nullptr, out);
}

// Round 4
// 189.923 us; speedup vs baseline: 2.0253x; 1.0648x over previous
//
#include <hip/hip_runtime.h>
#include <stdint.h>

#define T_SEQ 2048
#define NH 16
#define HD 64
#define M_DIM 4096      // B*T
#define K_DIM 1024      // C

typedef __attribute__((ext_vector_type(8))) short bf16x8;
typedef __attribute__((ext_vector_type(4))) float f32x4;
typedef __attribute__((ext_vector_type(4))) unsigned short u16x4;

__device__ __forceinline__ unsigned short f2bf(float f) {
  union { float f; uint32_t u; } x; x.f = f;
  uint32_t u = x.u;
  return (unsigned short)((u + 0x7fffu + ((u >> 16) & 1u)) >> 16);
}

__device__ __forceinline__ uint32_t cvtpk_bf16(float a, float b) {
  uint32_t r;
  asm("v_cvt_pk_bf16_f32 %0, %1, %2" : "=v"(r) : "v"(a), "v"(b));
  return r;
}

#define GLOAD16(g, l) __builtin_amdgcn_global_load_lds( \
    (const __attribute__((address_space(1))) unsigned int*)(g), \
    (__attribute__((address_space(3))) unsigned int*)(l), 16, 0, 0)

// ---- fused preprocessing: x->bf16, w_attn->bf16^T, w_proj->bf16^T ----
__device__ __forceinline__ void do_convert(const float* __restrict__ src,
                                           unsigned short* __restrict__ dst, int bid) {
  int idx = (bid * 256 + threadIdx.x) * 4;
  f32x4 v = *(const f32x4*)(src + idx);
  u16x4 o;
  #pragma unroll
  for (int i = 0; i < 4; ++i) o[i] = f2bf(v[i]);
  *(u16x4*)(dst + idx) = o;
}

__device__ __forceinline__ void do_transpose(const float* __restrict__ src,
                                             unsigned short* __restrict__ dst,
                                             int R, int Cn, int bx, int by,
                                             float (*tile)[65]) {
  const int r0 = by * 64, c0 = bx * 64;
  const int t = threadIdx.x;
  const int rr = t >> 4;
  const int c4 = (t & 15) * 4;
  #pragma unroll
  for (int p = 0; p < 4; ++p) {
    f32x4 v = *(const f32x4*)(src + (size_t)(r0 + p * 16 + rr) * Cn + c0 + c4);
    #pragma unroll
    for (int i = 0; i < 4; ++i) tile[p * 16 + rr][c4 + i] = v[i];
  }
  __syncthreads();
  #pragma unroll
  for (int p = 0; p < 4; ++p) {
    const int cl = p * 16 + rr;
    u16x4 o;
    #pragma unroll
    for (int i = 0; i < 4; ++i) o[i] = f2bf(tile[c4 + i][cl]);
    *(u16x4*)(dst + (size_t)(c0 + cl) * R + r0 + c4) = o;
  }
}

__global__ __launch_bounds__(256) void prep_kernel(
    const float* __restrict__ x, unsigned short* __restrict__ xb,
    const float* __restrict__ w_attn, unsigned short* __restrict__ wqkvT,
    const float* __restrict__ w_proj, unsigned short* __restrict__ wprojT) {
  __shared__ float tile[64][65];
  const int b = blockIdx.x;
  if (b < 4096) {
    do_convert(x, xb, b);
  } else if (b < 4096 + 768) {
    const int bid = b - 4096;
    do_transpose(w_attn, wqkvT, 1024, 3072, bid % 48, bid / 48, tile);
  } else {
    const int bid = b - 4864;
    do_transpose(w_proj, wprojT, 1024, 1024, bid % 16, bid / 16, tile);
  }
}

// ---- 2-phase double-buffered GEMM: C[M][N] = A[M][K]*Bt[N][K]^T + bias ----
// BM = WM*64 rows, 128 cols, WM*2 waves (each 64x64 out). BK=32, dbuf LDS,
// next-tile global_load_lds issued BEFORE current tile's ds_read+MFMA (T3-min).
// MODE 0: split epilogue -> q(scaled)/k/vT bf16. MODE 1: fp32 out.
template <int MODE, int WM>
__global__ __launch_bounds__(WM * 128) void gemm2_kernel(
    const unsigned short* __restrict__ A,
    const unsigned short* __restrict__ Bt,
    const float* __restrict__ bias,
    unsigned short* __restrict__ qout,
    unsigned short* __restrict__ kout,
    unsigned short* __restrict__ vTout,
    float* __restrict__ fout) {
  constexpr int BM = WM * 64;
  constexpr int NT = WM * 128;          // threads
  constexpr int U_A = BM * 4;           // 16B staging units for A
  constexpr int NU = (U_A + 512) / NT;  // units per thread
  __shared__ __align__(16) unsigned short As[2][BM * 32];
  __shared__ __align__(16) unsigned short Bs[2][128 * 32];
  const int t = threadIdx.x;
  const int w = t >> 6, l = t & 63;
  const int wr = w >> 1, wc = w & 1;
  const int lr = l & 15, lg = l >> 4;
  const int br = blockIdx.y, bc = blockIdx.x;

  f32x4 acc[4][4];
  const f32x4 zf = {0.f, 0.f, 0.f, 0.f};
  #pragma unroll
  for (int i = 0; i < 4; ++i)
    #pragma unroll
    for (int j = 0; j < 4; ++j) acc[i][j] = zf;

  const unsigned short* Abase = A + (size_t)(br * BM) * K_DIM;
  const unsigned short* Bbase = Bt + (size_t)(bc * 128) * K_DIM;

  #define STAGE(k0, buf) do {                                                    \
    _Pragma("unroll")                                                            \
    for (int i = 0; i < NU; ++i) {                                               \
      const int u = i * NT + t;                                                  \
      if (u < U_A) {                                                             \
        GLOAD16(Abase + (size_t)(u >> 2) * K_DIM + (k0) + (u & 3) * 8,           \
                &As[buf][u * 8]);                                                \
      } else {                                                                   \
        const int v = u - U_A;                                                   \
        GLOAD16(Bbase + (size_t)(v >> 2) * K_DIM + (k0) + (v & 3) * 8,           \
                &Bs[buf][v * 8]);                                                \
      }                                                                          \
    }                                                                            \
  } while (0)

  #define COMPUTE(buf) do {                                                      \
    bf16x8 af[4], bfv[4];                                                        \
    _Pragma("unroll")                                                            \
    for (int f = 0; f < 4; ++f) {                                                \
      af[f]  = *(const bf16x8*)(&As[buf][(wr * 64 + f * 16 + lr) * 32 + lg * 8]);\
      bfv[f] = *(const bf16x8*)(&Bs[buf][(wc * 64 + f * 16 + lr) * 32 + lg * 8]);\
    }                                                                            \
    _Pragma("unroll")                                                            \
    for (int fr = 0; fr < 4; ++fr)                                               \
      _Pragma("unroll")                                                          \
      for (int fc = 0; fc < 4; ++fc)                                             \
        acc[fr][fc] = __builtin_amdgcn_mfma_f32_16x16x32_bf16(af[fr], bfv[fc],   \
                                                              acc[fr][fc], 0, 0, 0); \
  } while (0)

  STAGE(0, 0);
  __syncthreads();                      // implicit vmcnt(0) drain
  #pragma unroll 1
  for (int k0 = 0; k0 < K_DIM; k0 += 64) {
    if (k0 + 32 < K_DIM) STAGE(k0 + 32, 1);   // prefetch flies under compute
    COMPUTE(0);
    __syncthreads();
    if (k0 + 64 < K_DIM) STAGE(k0 + 64, 0);
    COMPUTE(1);
    __syncthreads();
  }
  #undef STAGE
  #undef COMPUTE

  #pragma unroll
  for (int fr = 0; fr < 4; ++fr) {
    #pragma unroll
    for (int fc = 0; fc < 4; ++fc) {
      const int m0 = br * BM + wr * 64 + fr * 16 + lg * 4;
      const int n  = bc * 128 + wc * 64 + fc * 16 + lr;
      if (MODE == 0) {
        const int which = n >> 10, rem = n & 1023;
        const int h = rem >> 6, d = rem & 63;
        const int b = m0 >> 11, tt0 = m0 & 2047;
        const int bh = b * NH + h;
        if (which == 2) {
          u16x4 pack;
          #pragma unroll
          for (int r = 0; r < 4; ++r) pack[r] = f2bf(acc[fr][fc][r] + bias[n]);
          *(u16x4*)(vTout + ((size_t)bh * HD + d) * T_SEQ + tt0) = pack;
        } else {
          unsigned short* o = (which == 0) ? qout : kout;
          const float sc = (which == 0) ? 0.18033688011112042f : 1.0f;  // 0.125*log2(e)
          #pragma unroll
          for (int r = 0; r < 4; ++r)
            o[((size_t)bh * T_SEQ + tt0 + r) * HD + d] = f2bf((acc[fr][fc][r] + bias[n]) * sc);
        }
      } else {
        #pragma unroll
        for (int r = 0; r < 4; ++r)
          fout[(size_t)(m0 + r) * 1024 + n] = acc[fr][fc][r] + bias[n];
      }
    }
  }
}

// ---- causal flash attention, v3: exp2-domain softmax + defer-max + cvt_pk ----
__global__ __launch_bounds__(256) void flash_attn_kernel(
    const unsigned short* __restrict__ qg,
    const unsigned short* __restrict__ kg,
    const unsigned short* __restrict__ vTg,
    unsigned short* __restrict__ yg) {
  __shared__ __align__(16) unsigned short Ks[2][64 * 64];
  __shared__ __align__(16) unsigned short Vs[2][64 * 64];
  __shared__ __align__(16) unsigned short P[4][16][64];

  const int t = threadIdx.x;
  const int w = t >> 6, l = t & 63;
  const int lr = l & 15, lg = l >> 4;
  const int lb = (blockIdx.x & 7) * 64 + (blockIdx.x >> 3);  // XCD swizzle
  const int pid = lb & 15;
  const int bh = lb >> 4;
  const int swz = lr & 7;

  const int srow0 = t >> 3;
  const int sch = t & 7;

  const size_t kgb = (size_t)bh * T_SEQ * HD;
  const size_t vgb = (size_t)bh * HD * T_SEQ;
  const f32x4 zf = {0.f, 0.f, 0.f, 0.f};

  #pragma unroll 1
  for (int ph = 0; ph < 2; ++ph) {
    const int qt = ph ? (31 - pid) : pid;
    const int nt = qt + 1;
    const int qw = qt * 64 + w * 16;
    const int qrow = qw + lr;

    const size_t qoff = ((size_t)bh * T_SEQ + qw + lr) * HD + lg * 8;
    const bf16x8 qf0 = *(const bf16x8*)(qg + qoff);      // pre-scaled by 0.125*log2e
    const bf16x8 qf1 = *(const bf16x8*)(qg + qoff + 32);

    f32x4 acc[4];
    #pragma unroll
    for (int i = 0; i < 4; ++i) acc[i] = zf;
    float m_run = 0.f;
    float l_part = 0.f;

    #pragma unroll
    for (int sh = 0; sh < 2; ++sh) {
      const int row = sh * 32 + srow0;
      const int sc = (sch ^ (row & 7)) * 8;
      GLOAD16(kg + kgb + (size_t)row * HD + sc, Ks[0] + row * 64 + sch * 8);
      GLOAD16(vTg + vgb + (size_t)row * T_SEQ + sc, Vs[0] + row * 64 + sch * 8);
    }
    __syncthreads();

    int cur = 0;
    #pragma unroll 1
    for (int it = 0; it < nt; ++it) {
      const int kv0 = it * 64;
      if (it + 1 < nt) {
        const int kvn = kv0 + 64;
        #pragma unroll
        for (int sh = 0; sh < 2; ++sh) {
          const int row = sh * 32 + srow0;
          const int sc = (sch ^ (row & 7)) * 8;
          GLOAD16(kg + kgb + (size_t)(kvn + row) * HD + sc, Ks[cur ^ 1] + row * 64 + sch * 8);
          GLOAD16(vTg + vgb + (size_t)row * T_SEQ + kvn + sc, Vs[cur ^ 1] + row * 64 + sch * 8);
        }
      }

      f32x4 s[4];
      __builtin_amdgcn_s_setprio(1);
      #pragma unroll
      for (int fc = 0; fc < 4; ++fc) {
        const unsigned short* kr = Ks[cur] + (fc * 16 + lr) * 64;
        const bf16x8 k0v = *(const bf16x8*)(kr + ((lg ^ swz) * 8));
        const bf16x8 k1v = *(const bf16x8*)(kr + (((lg + 4) ^ swz) * 8));
        f32x4 sv = zf;
        sv = __builtin_amdgcn_mfma_f32_16x16x32_bf16(k0v, qf0, sv, 0, 0, 0);
        sv = __builtin_amdgcn_mfma_f32_16x16x32_bf16(k1v, qf1, sv, 0, 0, 0);
        s[fc] = sv;
      }
      __builtin_amdgcn_s_setprio(0);

      if (it == nt - 1) {
        #pragma unroll
        for (int fc = 0; fc < 4; ++fc)
          #pragma unroll
          for (int r = 0; r < 4; ++r) {
            const int tkv = kv0 + fc * 16 + lg * 4 + r;
            if (tkv > qrow) s[fc][r] = -1e30f;
          }
      }

      float mt = s[0][0];
      #pragma unroll
      for (int fc = 0; fc < 4; ++fc)
        #pragma unroll
        for (int r = 0; r < 4; ++r) mt = fmaxf(mt, s[fc][r]);
      if (__any(mt > m_run + 8.f)) {
        float mrow = fmaxf(mt, __shfl_xor(mt, 16));
        mrow = fmaxf(mrow, __shfl_xor(mrow, 32));
        const float m_new = fmaxf(m_run, mrow);
        const float fac = __builtin_amdgcn_exp2f(m_run - m_new);
        l_part *= fac;
        float frs[4];
        #pragma unroll
        for (int r = 0; r < 4; ++r) frs[r] = __shfl(fac, lg * 4 + r);
        #pragma unroll
        for (int fd = 0; fd < 4; ++fd)
          #pragma unroll
          for (int r = 0; r < 4; ++r) acc[fd][r] *= frs[r];
        m_run = m_new;
      }

      #pragma unroll
      for (int fc = 0; fc < 4; ++fc) {
        float e0 = __builtin_amdgcn_exp2f(s[fc][0] - m_run);
        float e1 = __builtin_amdgcn_exp2f(s[fc][1] - m_run);
        float e2 = __builtin_amdgcn_exp2f(s[fc][2] - m_run);
        float e3 = __builtin_amdgcn_exp2f(s[fc][3] - m_run);
        l_part += (e0 + e1) + (e2 + e3);
        uint2 pk;
        pk.x = cvtpk_bf16(e0, e1);
        pk.y = cvtpk_bf16(e2, e3);
        *(uint2*)&P[w][lr][(fc * 16 + lg * 4) ^ ((lr & 3) << 4)] = pk;
      }

      const bf16x8 pa0 = *(const bf16x8*)&P[w][lr][(lg * 8) ^ ((lr & 3) << 4)];
      const bf16x8 pa1 = *(const bf16x8*)&P[w][lr][(32 + lg * 8) ^ ((lr & 3) << 4)];
      __builtin_amdgcn_s_setprio(1);
      #pragma unroll
      for (int fd = 0; fd < 4; ++fd) {
        const unsigned short* vr = Vs[cur] + (fd * 16 + lr) * 64;
        const bf16x8 v0 = *(const bf16x8*)(vr + ((lg ^ swz) * 8));
        const bf16x8 v1 = *(const bf16x8*)(vr + (((lg + 4) ^ swz) * 8));
        acc[fd] = __builtin_amdgcn_mfma_f32_16x16x32_bf16(pa0, v0, acc[fd], 0, 0, 0);
        acc[fd] = __builtin_amdgcn_mfma_f32_16x16x32_bf16(pa1, v1, acc[fd], 0, 0, 0);
      }
      __builtin_amdgcn_s_setprio(0);
      __syncthreads();
      cur ^= 1;
    }

    float lsum = l_part;
    lsum += __shfl_xor(lsum, 16);
    lsum += __shfl_xor(lsum, 32);

    const int b = bh >> 4, h = bh & 15;
    #pragma unroll
    for (int r = 0; r < 4; ++r) {
      const float lv = __shfl(lsum, lg * 4 + r);
      const float linv = 1.f / lv;
      const int tt = qw + lg * 4 + r;
      #pragma unroll
      for (int fd = 0; fd < 4; ++fd) {
        const int d = fd * 16 + lr;
        yg[(((size_t)b * T_SEQ + tt) * NH + h) * HD + d] = f2bf(acc[fd][r] * linv);
      }
    }
    __syncthreads();
  }
}

extern "C" void kernel_launch(void* const* d_in, const int* in_sizes, int n_in,
                              void* d_out, int out_size, void* d_ws, size_t ws_size,
                              hipStream_t stream) {
  (void)in_sizes; (void)n_in; (void)out_size; (void)ws_size;
  const float* x      = (const float*)d_in[0];
  const float* w_attn = (const float*)d_in[1];
  const float* b_attn = (const float*)d_in[2];
  const float* w_proj = (const float*)d_in[3];
  const float* b_proj = (const float*)d_in[4];
  float* out = (float*)d_out;

  char* ws = (char*)d_ws;
  unsigned short* xb     = (unsigned short*)(ws);                  // 8 MiB  [4096][1024]
  unsigned short* wqkvT  = (unsigned short*)(ws + (8ull  << 20));  // 6 MiB  [3072][1024]
  unsigned short* wprojT = (unsigned short*)(ws + (14ull << 20));  // 2 MiB  [1024][1024]
  unsigned short* qb     = (unsigned short*)(ws + (16ull << 20));  // 8 MiB  [BH][T][D]
  unsigned short* kb     = (unsigned short*)(ws + (24ull << 20));  // 8 MiB  [BH][T][D]
  unsigned short* vT     = (unsigned short*)(ws + (32ull << 20));  // 8 MiB  [BH][D][T]
  unsigned short* yb     = (unsigned short*)(ws + (40ull << 20));  // 8 MiB  [4096][1024]

  prep_kernel<<<5120, 256, 0, stream>>>(x, xb, w_attn, wqkvT, w_proj, wprojT);
  gemm2_kernel<0, 4><<<dim3(24, 16), 512, 0, stream>>>(xb, wqkvT, b_attn, qb, kb, vT, nullptr);
  flash_attn_kernel<<<512, 256, 0, stream>>>(qb, kb, vT, yb);
  gemm2_kernel<1, 2><<<dim3(8, 32), 256, 0, stream>>>(yb, wprojT, b_proj, nullptr, nullptr, nullptr, out);
}